// Round 4
// baseline (162.070 us; speedup 1.0000x reference)
//
#include <hip/hip_runtime.h>
#include <math.h>
#include <stdint.h>

#define B_     32
#define L_     16384
#define C_     128
#define KTOP   64
#define NCOL   (B_ * C_)     // 4096 columns
#define CAPMAX 512           // per-column candidate capacity (8 slots/lane * 64 lanes)
#define T0     2.25f         // filter threshold; E[count>T0] ~ 200/column, sd ~14
                             // P(count < 64) ~ 1e-21 per column

typedef float f32x4 __attribute__((ext_vector_type(4)));

// pack (value, index): high32 = float bits (v > 0 so bit pattern is monotonic
// in value), low32 = index. u64 compare == lexicographic (value, index) max,
// which matches JAX stable-argsort tie rule (largest indices win ties).
__device__ __forceinline__ uint64_t pack_cand(float v, int l) {
    return ((uint64_t)__float_as_uint(v) << 32) | (uint32_t)l;
}

// lexicographic (value, index) less-than (fallback path only)
__device__ __forceinline__ bool lex_lt(float v1, int i1, float v2, int i2) {
    return (v1 < v2) || ((v1 == v2) && (i1 < i2));
}

__device__ __forceinline__ void push_cand(int col, int l, float v,
                                          int* __restrict__ cnt,
                                          uint64_t* __restrict__ cand, int cap) {
    int p = atomicAdd(&cnt[col], 1);
    if (p < cap) {
        // nontemporal: avoid L2 write-allocate + cross-XCD line ping-pong
        __builtin_nontemporal_store(pack_cand(v, l), &cand[(size_t)col * cap + p]);
    }
}

// Zero the per-column candidate counters (hipMemsetAsync is slow in-graph).
__global__ __launch_bounds__(256) void k_zero(int* __restrict__ cnt) {
    cnt[blockIdx.x * 256 + threadIdx.x] = 0;
}

// Pass 1: stream all of x (coalesced float4, nontemporal), compact values > T0
// per column. grid: (L_/256, B_), block: 256 threads (8 rows x 32 float4-lanes)
__global__ __launch_bounds__(256) void k_filter(const float* __restrict__ x,
                                                int* __restrict__ cnt,
                                                uint64_t* __restrict__ cand,
                                                int cap) {
    const int b  = blockIdx.y;
    const int l0 = blockIdx.x * 256;
    const int r  = threadIdx.x >> 5;     // 0..7 row within group
    const int c4 = threadIdx.x & 31;     // float4 slot within row (0..31)
    const f32x4* xb = (const f32x4*)x + (size_t)b * L_ * (C_ / 4);
    const int cbase = b * C_ + c4 * 4;

    for (int l = l0 + r; l < l0 + 256; l += 8) {
        f32x4 v = __builtin_nontemporal_load((f32x4*)&xb[(size_t)l * (C_ / 4) + c4]);
        if (v.x > T0) push_cand(cbase + 0, l, v.x, cnt, cand, cap);
        if (v.y > T0) push_cand(cbase + 1, l, v.y, cnt, cand, cap);
        if (v.z > T0) push_cand(cbase + 2, l, v.z, cnt, cand, cap);
        if (v.w > T0) push_cand(cbase + 3, l, v.w, cnt, cand, cap);
    }
}

// Pass 2: ONE WAVE per column (4 columns per 256-block). Register tournament
// on packed u64 keys: 64 rounds of {max over 8 regs -> shfl_xor butterfly ->
// clear winner}. No LDS, no barriers. Temporal order restored by index-rank.
// Fallback (count < KTOP or overflow): exact lexicographic descent on x.
__global__ __launch_bounds__(256) void k_select(const float* __restrict__ x,
                                                const int* __restrict__ cnt,
                                                const uint64_t* __restrict__ cand,
                                                float* __restrict__ out,
                                                int cap) {
    const int wave = threadIdx.x >> 6;           // 0..3
    const int lane = threadIdx.x & 63;
    const int col  = blockIdx.x * 4 + wave;
    const int b    = col >> 7;
    const int c    = col & (C_ - 1);

    const int n = (cap > 0) ? cnt[col] : 0;

    float keepv = 0.0f;
    int   keepi = 0;

    if (n >= KTOP && n <= cap) {
        // ---- fast path: candidates into registers (8 u64 slots/lane) ----
        uint64_t s[8];
#pragma unroll
        for (int i = 0; i < 8; ++i) {
            int p = lane + i * 64;
            s[i] = (p < n) ? cand[(size_t)col * cap + p] : 0ull;  // 0 sorts last
        }
        for (int k = 0; k < KTOP; ++k) {
            uint64_t best = s[0];
#pragma unroll
            for (int i = 1; i < 8; ++i) best = (s[i] > best) ? s[i] : best;
#pragma unroll
            for (int off = 32; off; off >>= 1) {
                uint64_t o = __shfl_xor((unsigned long long)best, off, 64);
                best = (o > best) ? o : best;
            }
            if (lane == k) {
                keepv = __uint_as_float((uint32_t)(best >> 32));
                keepi = (int)(uint32_t)(best & 0xffffffffull);
            }
            // clear winner (keys unique: index field differs)
#pragma unroll
            for (int i = 0; i < 8; ++i) if (s[i] == best) s[i] = 0ull;
        }
    } else {
        // ---- exact fallback: lexicographic-descent argmax, 64 rounds ----
        const float* xc = x + (size_t)b * L_ * C_ + c;
        float pv = INFINITY;
        int   pi = 0x7fffffff;
        for (int k = 0; k < KTOP; ++k) {
            float bv = -INFINITY;
            int   bi = -1;
            for (int l = lane; l < L_; l += 64) {
                float vv = xc[(size_t)l * C_];
                if (lex_lt(vv, l, pv, pi) && lex_lt(bv, bi, vv, l)) {
                    bv = vv; bi = l;
                }
            }
#pragma unroll
            for (int off = 32; off; off >>= 1) {
                float ov = __shfl_xor(bv, off, 64);
                int   oi = __shfl_xor(bi, off, 64);
                if (lex_lt(bv, bi, ov, oi)) { bv = ov; bi = oi; }
            }
            pv = bv; pi = bi;
            if (lane == k) { keepv = bv; keepi = bi; }
        }
    }

    // rank this lane's winner by original index -> output row (temporal order)
    int pos = 0;
    for (int j = 0; j < KTOP; ++j) {
        int oi = __shfl(keepi, j, 64);
        pos += (oi < keepi);
    }
    out[((size_t)b * KTOP + pos) * C_ + c] = keepv;
}

extern "C" void kernel_launch(void* const* d_in, const int* in_sizes, int n_in,
                              void* d_out, int out_size, void* d_ws, size_t ws_size,
                              hipStream_t stream) {
    (void)in_sizes; (void)n_in; (void)out_size;
    const float* x  = (const float*)d_in[0];
    float*      out = (float*)d_out;

    int*   cnt       = (int*)d_ws;
    size_t cnt_bytes = (size_t)NCOL * sizeof(int);

    // size the candidate buffer from the workspace we actually have
    int cap = 0;
    if (ws_size > cnt_bytes) {
        size_t rem = ws_size - cnt_bytes;
        size_t c   = rem / ((size_t)NCOL * 8);  // 8 B per packed slot
        cap = (c > CAPMAX) ? CAPMAX : (int)c;
    }
    uint64_t* cand = (uint64_t*)((char*)d_ws + cnt_bytes);

    if (cap >= KTOP) {
        k_zero<<<NCOL / 256, 256, 0, stream>>>(cnt);
        dim3 g1(L_ / 256, B_);
        k_filter<<<g1, 256, 0, stream>>>(x, cnt, cand, cap);
    } else {
        cap = 0;  // workspace too small: k_select takes exact fallback for all
    }

    k_select<<<NCOL / 4, 256, 0, stream>>>(x, cnt, cand, out, cap);
}

// Round 5
// 110.214 us; speedup vs baseline: 1.4705x; 1.4705x over previous
//
#include <hip/hip_runtime.h>
#include <math.h>
#include <stdint.h>

#define B_     32
#define L_     16384
#define C_     128
#define KTOP   64
#define NCOL   (B_ * C_)     // 4096 columns
#define CAPMAX 512           // per-column candidate capacity (8 slots/lane * 64 lanes)
#define CSTR   32            // cnt stride in ints: one counter per 128 B L2 line
#define LSLOT  16            // LDS candidate slots per column per block
#define T0     2.25f         // filter threshold; E[count>T0] ~ 200/column, sd ~14
                             // P(count < 64) ~ 1e-21 per column

typedef float f32x4 __attribute__((ext_vector_type(4)));

// pack (value, index): high32 = float bits (v > T0 > 0 so bit pattern is
// monotonic in value), low32 = index. u64 max == lexicographic (value, index)
// max == JAX stable-argsort tie rule (largest indices win ties).
__device__ __forceinline__ uint64_t pack_cand(float v, int l) {
    return ((uint64_t)__float_as_uint(v) << 32) | (uint32_t)l;
}

// lexicographic (value, index) less-than (fallback path only)
__device__ __forceinline__ bool lex_lt(float v1, int i1, float v2, int i2) {
    return (v1 < v2) || ((v1 == v2) && (i1 < i2));
}

// Zero the padded per-column counters (512 KB).
__global__ __launch_bounds__(256) void k_zero(int* __restrict__ cnt) {
    cnt[blockIdx.x * 256 + threadIdx.x] = 0;
}

// Pass 1: stream all of x (coalesced float4), compact values > T0 per column.
// Candidates are counted in LDS (per-CU atomics), then ONE padded global
// atomic per (block, column) reserves an append range; drain with plain
// stores. Rare LDS overflow (P ~ 1e-8 per block-col) falls back to a direct
// padded global atomic push -- order in the buffer is irrelevant (full sort
// in pass 2). grid: (L_/256, B_), block: 256 threads.
__global__ __launch_bounds__(256) void k_filter(const float* __restrict__ x,
                                                int* __restrict__ cnt,
                                                uint64_t* __restrict__ cand,
                                                int cap) {
    __shared__ int      lcnt[C_];
    __shared__ uint64_t lbuf[C_][LSLOT + 1];   // +1: break 128B-stride bank aliasing

    const int tid = threadIdx.x;
    const int b   = blockIdx.y;
    const int l0  = blockIdx.x * 256;
    const int r   = tid >> 5;                  // 0..7 row within group
    const int c4  = tid & 31;                  // float4 slot within row
    const f32x4* xb = (const f32x4*)x + (size_t)b * L_ * (C_ / 4);
    const int clbase = c4 * 4;

    if (tid < C_) lcnt[tid] = 0;
    __syncthreads();

    for (int l = l0 + r; l < l0 + 256; l += 8) {
        f32x4 v = xb[(size_t)l * (C_ / 4) + c4];
#pragma unroll
        for (int j = 0; j < 4; ++j) {
            float vv = (j == 0) ? v.x : (j == 1) ? v.y : (j == 2) ? v.z : v.w;
            if (vv > T0) {
                int cl = clbase + j;
                int p  = atomicAdd(&lcnt[cl], 1);
                if (p < LSLOT) {
                    lbuf[cl][p] = pack_cand(vv, l);
                } else {  // rare overflow: direct global append
                    int g = atomicAdd(&cnt[(b * C_ + cl) * CSTR], 1);
                    if (g < cap) cand[(size_t)(b * C_ + cl) * cap + g] = pack_cand(vv, l);
                }
            }
        }
    }
    __syncthreads();

    if (tid < C_) {
        int m = lcnt[tid];
        m = (m > LSLOT) ? LSLOT : m;
        if (m > 0) {
            int col  = b * C_ + tid;
            int base = atomicAdd(&cnt[col * CSTR], m);
            for (int j = 0; j < m; ++j) {
                int p = base + j;
                if (p < cap) cand[(size_t)col * cap + p] = lbuf[tid][j];
            }
        }
    }
}

// Pass 2: ONE WAVE per column (4 columns per 256-block). Register tournament
// on packed u64 keys: 64 rounds of {max over 8 regs -> shfl_xor butterfly ->
// clear winner}. No LDS, no barriers. Temporal order restored by index-rank.
// Fallback (count < KTOP or overflow): exact lexicographic descent on x.
__global__ __launch_bounds__(256) void k_select(const float* __restrict__ x,
                                                const int* __restrict__ cnt,
                                                const uint64_t* __restrict__ cand,
                                                float* __restrict__ out,
                                                int cap) {
    const int wave = threadIdx.x >> 6;           // 0..3
    const int lane = threadIdx.x & 63;
    const int col  = blockIdx.x * 4 + wave;
    const int b    = col >> 7;
    const int c    = col & (C_ - 1);

    const int n = (cap > 0) ? cnt[col * CSTR] : 0;

    float keepv = 0.0f;
    int   keepi = 0;

    if (n >= KTOP && n <= cap) {
        // ---- fast path: candidates into registers (8 u64 slots/lane) ----
        uint64_t s[8];
#pragma unroll
        for (int i = 0; i < 8; ++i) {
            int p = lane + i * 64;
            s[i] = (p < n) ? cand[(size_t)col * cap + p] : 0ull;  // 0 sorts last
        }
        for (int k = 0; k < KTOP; ++k) {
            uint64_t best = s[0];
#pragma unroll
            for (int i = 1; i < 8; ++i) best = (s[i] > best) ? s[i] : best;
#pragma unroll
            for (int off = 32; off; off >>= 1) {
                uint64_t o = __shfl_xor((unsigned long long)best, off, 64);
                best = (o > best) ? o : best;
            }
            if (lane == k) {
                keepv = __uint_as_float((uint32_t)(best >> 32));
                keepi = (int)(uint32_t)(best & 0xffffffffull);
            }
            // clear winner (keys unique: index field differs)
#pragma unroll
            for (int i = 0; i < 8; ++i) if (s[i] == best) s[i] = 0ull;
        }
    } else {
        // ---- exact fallback: lexicographic-descent argmax, 64 rounds ----
        const float* xc = x + (size_t)b * L_ * C_ + c;
        float pv = INFINITY;
        int   pi = 0x7fffffff;
        for (int k = 0; k < KTOP; ++k) {
            float bv = -INFINITY;
            int   bi = -1;
            for (int l = lane; l < L_; l += 64) {
                float vv = xc[(size_t)l * C_];
                if (lex_lt(vv, l, pv, pi) && lex_lt(bv, bi, vv, l)) {
                    bv = vv; bi = l;
                }
            }
#pragma unroll
            for (int off = 32; off; off >>= 1) {
                float ov = __shfl_xor(bv, off, 64);
                int   oi = __shfl_xor(bi, off, 64);
                if (lex_lt(bv, bi, ov, oi)) { bv = ov; bi = oi; }
            }
            pv = bv; pi = bi;
            if (lane == k) { keepv = bv; keepi = bi; }
        }
    }

    // rank this lane's winner by original index -> output row (temporal order)
    int pos = 0;
    for (int j = 0; j < KTOP; ++j) {
        int oi = __shfl(keepi, j, 64);
        pos += (oi < keepi);
    }
    out[((size_t)b * KTOP + pos) * C_ + c] = keepv;
}

extern "C" void kernel_launch(void* const* d_in, const int* in_sizes, int n_in,
                              void* d_out, int out_size, void* d_ws, size_t ws_size,
                              hipStream_t stream) {
    (void)in_sizes; (void)n_in; (void)out_size;
    const float* x  = (const float*)d_in[0];
    float*      out = (float*)d_out;

    int*   cnt       = (int*)d_ws;
    size_t cnt_bytes = (size_t)NCOL * CSTR * sizeof(int);   // 512 KB, padded

    // size the candidate buffer from the workspace we actually have
    int cap = 0;
    if (ws_size > cnt_bytes) {
        size_t rem = ws_size - cnt_bytes;
        size_t c   = rem / ((size_t)NCOL * 8);  // 8 B per packed slot
        cap = (c > CAPMAX) ? CAPMAX : (int)c;
    }
    uint64_t* cand = (uint64_t*)((char*)d_ws + cnt_bytes);

    if (cap >= KTOP) {
        k_zero<<<(NCOL * CSTR) / 256, 256, 0, stream>>>(cnt);
        dim3 g1(L_ / 256, B_);
        k_filter<<<g1, 256, 0, stream>>>(x, cnt, cand, cap);
    } else {
        cap = 0;  // workspace too small: k_select takes exact fallback for all
    }

    k_select<<<NCOL / 4, 256, 0, stream>>>(x, cnt, cand, out, cap);
}

// Round 7
// 89.389 us; speedup vs baseline: 1.8131x; 1.2330x over previous
//
#include <hip/hip_runtime.h>
#include <math.h>
#include <stdint.h>

#define B_     32
#define L_     16384
#define C_     128
#define KTOP   64
#define NCOL   (B_ * C_)     // 4096 columns
#define CAPMAX 512           // per-column candidate capacity (8 slots/lane * 64 lanes)
#define CSTR   32            // cnt stride in ints: one counter per 128 B L2 line
#define LSLOT  16            // LDS candidate slots per column per block
#define T0     2.25f         // filter threshold; E[count>T0] ~ 200/column, sd ~14
                             // P(count < 64) ~ 1e-21 per column

typedef float f32x4 __attribute__((ext_vector_type(4)));

// pack (value, index): high32 = float bits (v > T0 > 0 so bit pattern is
// monotonic in value), low32 = index. u64 max == lexicographic (value, index)
// max == JAX stable-argsort tie rule (largest indices win ties).
__device__ __forceinline__ uint64_t pack_cand(float v, int l) {
    return ((uint64_t)__float_as_uint(v) << 32) | (uint32_t)l;
}

// lexicographic (value, index) less-than (fallback path only)
__device__ __forceinline__ bool lex_lt(float v1, int i1, float v2, int i2) {
    return (v1 < v2) || ((v1 == v2) && (i1 < i2));
}

// Zero the padded per-column counters (512 KB).
__global__ __launch_bounds__(256) void k_zero(int* __restrict__ cnt) {
    cnt[blockIdx.x * 256 + threadIdx.x] = 0;
}

// Pass 1 (UNCHANGED from R5 -- proven piece): stream x, LDS-batched compact of
// values > T0 per column; one padded global atomic per (block, column).
__global__ __launch_bounds__(256) void k_filter(const float* __restrict__ x,
                                                int* __restrict__ cnt,
                                                uint64_t* __restrict__ cand,
                                                int cap) {
    __shared__ int      lcnt[C_];
    __shared__ uint64_t lbuf[C_][LSLOT + 1];   // +1: break 128B-stride bank aliasing

    const int tid = threadIdx.x;
    const int b   = blockIdx.y;
    const int l0  = blockIdx.x * 256;
    const int r   = tid >> 5;                  // 0..7 row within group
    const int c4  = tid & 31;                  // float4 slot within row
    const f32x4* xb = (const f32x4*)x + (size_t)b * L_ * (C_ / 4);
    const int clbase = c4 * 4;

    if (tid < C_) lcnt[tid] = 0;
    __syncthreads();

    for (int l = l0 + r; l < l0 + 256; l += 8) {
        f32x4 v = xb[(size_t)l * (C_ / 4) + c4];
#pragma unroll
        for (int j = 0; j < 4; ++j) {
            float vv = (j == 0) ? v.x : (j == 1) ? v.y : (j == 2) ? v.z : v.w;
            if (vv > T0) {
                int cl = clbase + j;
                int p  = atomicAdd(&lcnt[cl], 1);
                if (p < LSLOT) {
                    lbuf[cl][p] = pack_cand(vv, l);
                } else {  // rare overflow: direct global append
                    int g = atomicAdd(&cnt[(b * C_ + cl) * CSTR], 1);
                    if (g < cap) cand[(size_t)(b * C_ + cl) * cap + g] = pack_cand(vv, l);
                }
            }
        }
    }
    __syncthreads();

    if (tid < C_) {
        int m = lcnt[tid];
        m = (m > LSLOT) ? LSLOT : m;
        if (m > 0) {
            int col  = b * C_ + tid;
            int base = atomicAdd(&cnt[col * CSTR], m);
            for (int j = 0; j < m; ++j) {
                int p = base + j;
                if (p < cap) cand[(size_t)col * cap + p] = lbuf[tid][j];
            }
        }
    }
}

// Pass 2: ONE WAVE per column. Full in-register bitonic sort of 512 packed
// u64 keys (virtual index v = reg*64 + lane; cross-lane exchanges via
// shfl_xor for j<=32, register compare-exchange for j>=64). Descending sort
// puts the top-64 keys at v in [0,64) == reg 0 of every lane.
// R6 bugfix: cross-lane keep-condition now includes the lane-parity term
// (upper = lane&j) -- R6 had both partners keeping the max.
__global__ __launch_bounds__(256) void k_select(const float* __restrict__ x,
                                                const int* __restrict__ cnt,
                                                const uint64_t* __restrict__ cand,
                                                float* __restrict__ out,
                                                int cap) {
    const int wave = threadIdx.x >> 6;           // 0..3
    const int lane = threadIdx.x & 63;
    const int col  = blockIdx.x * 4 + wave;
    const int b    = col >> 7;
    const int c    = col & (C_ - 1);

    const int n = (cap > 0) ? cnt[col * CSTR] : 0;

    float keepv = 0.0f;
    int   keepi = 0;

    if (n >= KTOP && n <= cap) {
        // ---- fast path: candidates into registers (8 u64 slots/lane) ----
        uint64_t s[8];
#pragma unroll
        for (int i = 0; i < 8; ++i) {
            int p = lane + i * 64;
            s[i] = (p < n) ? cand[(size_t)col * cap + p] : 0ull;  // 0 sorts last
        }
        // bitonic sort, descending over virtual index v = r*64 + lane
#pragma unroll
        for (int k = 2; k <= 512; k <<= 1) {
#pragma unroll
            for (int j = k >> 1; j >= 64; j >>= 1) {        // intra-lane CE
                const int rd = j >> 6;
#pragma unroll
                for (int r = 0; r < 8; ++r) {
                    if ((r & rd) == 0) {
                        const int q = r | rd;
                        const bool km = (((r * 64) & k) == 0);  // compile-time
                        uint64_t hi = (s[r] > s[q]) ? s[r] : s[q];
                        uint64_t lo = (s[r] > s[q]) ? s[q] : s[r];
                        s[r] = km ? hi : lo;
                        s[q] = km ? lo : hi;
                    }
                }
            }
#pragma unroll
            for (int j = (k >> 1) > 32 ? 32 : (k >> 1); j >= 1; j >>= 1) {  // cross-lane CE
                const bool upper = (lane & j) != 0;
#pragma unroll
                for (int r = 0; r < 8; ++r) {
                    uint64_t o = __shfl_xor((unsigned long long)s[r], j, 64);
                    const bool km = (((r * 64 + lane) & k) == 0);  // descending block?
                    const bool take_max = (km != upper);
                    const bool gt = s[r] > o;
                    s[r] = (take_max == gt) ? s[r] : o;
                }
            }
        }
        // top-64 now in s[0] of each lane (v = lane in [0,64))
        keepv = __uint_as_float((uint32_t)(s[0] >> 32));
        keepi = (int)(uint32_t)(s[0] & 0xffffffffull);
    } else {
        // ---- exact fallback: lexicographic-descent argmax, 64 rounds ----
        const float* xc = x + (size_t)b * L_ * C_ + c;
        float pv = INFINITY;
        int   pi = 0x7fffffff;
        for (int k = 0; k < KTOP; ++k) {
            float bv = -INFINITY;
            int   bi = -1;
            for (int l = lane; l < L_; l += 64) {
                float vv = xc[(size_t)l * C_];
                if (lex_lt(vv, l, pv, pi) && lex_lt(bv, bi, vv, l)) {
                    bv = vv; bi = l;
                }
            }
#pragma unroll
            for (int off = 32; off; off >>= 1) {
                float ov = __shfl_xor(bv, off, 64);
                int   oi = __shfl_xor(bi, off, 64);
                if (lex_lt(bv, bi, ov, oi)) { bv = ov; bi = oi; }
            }
            pv = bv; pi = bi;
            if (lane == k) { keepv = bv; keepi = bi; }
        }
    }

    // rank this lane's winner by original index -> output row (temporal order)
    int pos = 0;
    for (int j = 0; j < KTOP; ++j) {
        int oi = __shfl(keepi, j, 64);
        pos += (oi < keepi);
    }
    out[((size_t)b * KTOP + pos) * C_ + c] = keepv;
}

extern "C" void kernel_launch(void* const* d_in, const int* in_sizes, int n_in,
                              void* d_out, int out_size, void* d_ws, size_t ws_size,
                              hipStream_t stream) {
    (void)in_sizes; (void)n_in; (void)out_size;
    const float* x  = (const float*)d_in[0];
    float*      out = (float*)d_out;

    int*   cnt       = (int*)d_ws;
    size_t cnt_bytes = (size_t)NCOL * CSTR * sizeof(int);   // 512 KB, padded

    // size the candidate buffer from the workspace we actually have
    int cap = 0;
    if (ws_size > cnt_bytes) {
        size_t rem = ws_size - cnt_bytes;
        size_t c   = rem / ((size_t)NCOL * 8);  // 8 B per packed slot
        cap = (c > CAPMAX) ? CAPMAX : (int)c;
    }
    uint64_t* cand = (uint64_t*)((char*)d_ws + cnt_bytes);

    if (cap >= KTOP) {
        k_zero<<<(NCOL * CSTR) / 256, 256, 0, stream>>>(cnt);
        dim3 g1(L_ / 256, B_);
        k_filter<<<g1, 256, 0, stream>>>(x, cnt, cand, cap);
    } else {
        cap = 0;  // workspace too small: k_select takes exact fallback for all
    }

    k_select<<<NCOL / 4, 256, 0, stream>>>(x, cnt, cand, out, cap);
}

// Round 8
// 70.836 us; speedup vs baseline: 2.2879x; 1.2619x over previous
//
#include <hip/hip_runtime.h>
#include <math.h>
#include <stdint.h>

#define B_     32
#define L_     16384
#define C_     128
#define KTOP   64
#define NCOL   (B_ * C_)     // 4096 columns
#define CAPMAX 256           // per-column candidate capacity (4 slots/lane * 64 lanes)
#define CSTR   32            // cnt stride in ints: one counter per 128 B L2 line
#define LSLOT  16            // LDS candidate slots per column per block
#define T0     2.42f         // P(N(0,1)>T0)=0.00776 -> mean n~127, sd~11.2
                             // P(n<64) ~ 7.6e-9/col (3e-5 overall); P(n>256) ~ 0 (11.5 sigma)

typedef float f32x4 __attribute__((ext_vector_type(4)));

// pack (value, index): high32 = float bits (v > T0 > 0 so bit pattern is
// monotonic in value), low32 = index. u64 max == lexicographic (value, index)
// max == JAX stable-argsort tie rule (largest indices win ties).
__device__ __forceinline__ uint64_t pack_cand(float v, int l) {
    return ((uint64_t)__float_as_uint(v) << 32) | (uint32_t)l;
}

// lexicographic (value, index) less-than (fallback path only)
__device__ __forceinline__ bool lex_lt(float v1, int i1, float v2, int i2) {
    return (v1 < v2) || ((v1 == v2) && (i1 < i2));
}

// Zero the padded per-column counters (512 KB).
__global__ __launch_bounds__(256) void k_zero(int* __restrict__ cnt) {
    cnt[blockIdx.x * 256 + threadIdx.x] = 0;
}

// Pass 1: stream x (2 float4 loads in flight per thread), LDS-batched compact
// of values > T0 per column; one padded global atomic per (block, column).
__global__ __launch_bounds__(256) void k_filter(const float* __restrict__ x,
                                                int* __restrict__ cnt,
                                                uint64_t* __restrict__ cand,
                                                int cap) {
    __shared__ int      lcnt[C_];
    __shared__ uint64_t lbuf[C_][LSLOT + 1];   // +1: break 128B-stride bank aliasing

    const int tid = threadIdx.x;
    const int b   = blockIdx.y;
    const int l0  = blockIdx.x * 256;
    const int r   = tid >> 5;                  // 0..7 row within group
    const int c4  = tid & 31;                  // float4 slot within row
    const f32x4* xb = (const f32x4*)x + (size_t)b * L_ * (C_ / 4);
    const int clbase = c4 * 4;

    if (tid < C_) lcnt[tid] = 0;
    __syncthreads();

    for (int l = l0 + r; l < l0 + 256; l += 16) {
        f32x4 v0 = xb[(size_t)l * (C_ / 4) + c4];
        f32x4 v1 = xb[(size_t)(l + 8) * (C_ / 4) + c4];
#pragma unroll
        for (int h = 0; h < 2; ++h) {
            const f32x4 v = h ? v1 : v0;
            const int   lr = l + h * 8;
#pragma unroll
            for (int j = 0; j < 4; ++j) {
                float vv = (j == 0) ? v.x : (j == 1) ? v.y : (j == 2) ? v.z : v.w;
                if (vv > T0) {
                    int cl = clbase + j;
                    int p  = atomicAdd(&lcnt[cl], 1);
                    if (p < LSLOT) {
                        lbuf[cl][p] = pack_cand(vv, lr);
                    } else {  // rare overflow: direct global append
                        int g = atomicAdd(&cnt[(b * C_ + cl) * CSTR], 1);
                        if (g < cap) cand[(size_t)(b * C_ + cl) * cap + g] = pack_cand(vv, lr);
                    }
                }
            }
        }
    }
    __syncthreads();

    if (tid < C_) {
        int m = lcnt[tid];
        m = (m > LSLOT) ? LSLOT : m;
        if (m > 0) {
            int col  = b * C_ + tid;
            int base = atomicAdd(&cnt[col * CSTR], m);
            for (int j = 0; j < m; ++j) {
                int p = base + j;
                if (p < cap) cand[(size_t)col * cap + p] = lbuf[tid][j];
            }
        }
    }
}

// Pass 2: ONE WAVE per column. In-register bitonic sort of 256 packed u64
// keys (4 regs/lane; virtual index v = r*64 + lane). Descending sort puts the
// top-64 at v in [0,64) == reg 0. Then a 64-lane ascending bitonic sort by
// index restores temporal order (replaces the 64-shuffle rank loop).
__global__ __launch_bounds__(256) void k_select(const float* __restrict__ x,
                                                const int* __restrict__ cnt,
                                                const uint64_t* __restrict__ cand,
                                                float* __restrict__ out,
                                                int cap) {
    const int wave = threadIdx.x >> 6;           // 0..3
    const int lane = threadIdx.x & 63;
    const int col  = blockIdx.x * 4 + wave;
    const int b    = col >> 7;
    const int c    = col & (C_ - 1);

    const int n = (cap > 0) ? cnt[col * CSTR] : 0;

    float keepv = 0.0f;
    int   keepi = 0;

    if (n >= KTOP && n <= cap) {
        // ---- fast path: candidates into registers (4 u64 slots/lane) ----
        uint64_t s[4];
#pragma unroll
        for (int i = 0; i < 4; ++i) {
            int p = lane + i * 64;
            s[i] = (p < n) ? cand[(size_t)col * cap + p] : 0ull;  // 0 sorts last
        }
        // bitonic sort, descending over virtual index v = r*64 + lane
#pragma unroll
        for (int k = 2; k <= 256; k <<= 1) {
#pragma unroll
            for (int j = k >> 1; j >= 64; j >>= 1) {        // intra-lane CE
                const int rd = j >> 6;
#pragma unroll
                for (int r = 0; r < 4; ++r) {
                    if ((r & rd) == 0) {
                        const int q = r | rd;
                        const bool km = (((r * 64) & k) == 0);  // compile-time
                        uint64_t hi = (s[r] > s[q]) ? s[r] : s[q];
                        uint64_t lo = (s[r] > s[q]) ? s[q] : s[r];
                        s[r] = km ? hi : lo;
                        s[q] = km ? lo : hi;
                    }
                }
            }
#pragma unroll
            for (int j = (k >> 1) > 32 ? 32 : (k >> 1); j >= 1; j >>= 1) {  // cross-lane CE
                const bool upper = (lane & j) != 0;
#pragma unroll
                for (int r = 0; r < 4; ++r) {
                    uint64_t o = __shfl_xor((unsigned long long)s[r], j, 64);
                    const bool km = (((r * 64 + lane) & k) == 0);  // descending block?
                    const bool take_max = (km != upper);
                    const bool gt = s[r] > o;
                    s[r] = (take_max == gt) ? s[r] : o;
                }
            }
        }
        // top-64 now in s[0] of each lane (v = lane in [0,64))
        keepv = __uint_as_float((uint32_t)(s[0] >> 32));
        keepi = (int)(uint32_t)(s[0] & 0xffffffffull);
    } else {
        // ---- exact fallback: lexicographic-descent argmax, 64 rounds ----
        const float* xc = x + (size_t)b * L_ * C_ + c;
        float pv = INFINITY;
        int   pi = 0x7fffffff;
        for (int k = 0; k < KTOP; ++k) {
            float bv = -INFINITY;
            int   bi = -1;
            for (int l = lane; l < L_; l += 64) {
                float vv = xc[(size_t)l * C_];
                if (lex_lt(vv, l, pv, pi) && lex_lt(bv, bi, vv, l)) {
                    bv = vv; bi = l;
                }
            }
#pragma unroll
            for (int off = 32; off; off >>= 1) {
                float ov = __shfl_xor(bv, off, 64);
                int   oi = __shfl_xor(bi, off, 64);
                if (lex_lt(bv, bi, ov, oi)) { bv = ov; bi = oi; }
            }
            pv = bv; pi = bi;
            if (lane == k) { keepv = bv; keepi = bi; }
        }
    }

    // temporal reorder: 64-lane ascending bitonic sort on key2 = (index, value)
    // (indices unique -> strict order). Lane i then holds output row i.
    uint64_t key2 = ((uint64_t)(uint32_t)keepi << 32) | __float_as_uint(keepv);
#pragma unroll
    for (int k = 2; k <= 64; k <<= 1) {
#pragma unroll
        for (int j = k >> 1; j >= 1; j >>= 1) {
            const bool upper = (lane & j) != 0;
            uint64_t o = __shfl_xor((unsigned long long)key2, j, 64);
            const bool km = ((lane & k) != 0);      // ascending block?
            const bool take_max = (km != upper);
            const bool gt = key2 > o;
            key2 = (take_max == gt) ? key2 : o;
        }
    }
    out[((size_t)b * KTOP + lane) * C_ + c] =
        __uint_as_float((uint32_t)(key2 & 0xffffffffull));
}

extern "C" void kernel_launch(void* const* d_in, const int* in_sizes, int n_in,
                              void* d_out, int out_size, void* d_ws, size_t ws_size,
                              hipStream_t stream) {
    (void)in_sizes; (void)n_in; (void)out_size;
    const float* x  = (const float*)d_in[0];
    float*      out = (float*)d_out;

    int*   cnt       = (int*)d_ws;
    size_t cnt_bytes = (size_t)NCOL * CSTR * sizeof(int);   // 512 KB, padded

    // size the candidate buffer from the workspace we actually have
    int cap = 0;
    if (ws_size > cnt_bytes) {
        size_t rem = ws_size - cnt_bytes;
        size_t c   = rem / ((size_t)NCOL * 8);  // 8 B per packed slot
        cap = (c > CAPMAX) ? CAPMAX : (int)c;
    }
    uint64_t* cand = (uint64_t*)((char*)d_ws + cnt_bytes);

    if (cap >= KTOP) {
        k_zero<<<(NCOL * CSTR) / 256, 256, 0, stream>>>(cnt);
        dim3 g1(L_ / 256, B_);
        k_filter<<<g1, 256, 0, stream>>>(x, cnt, cand, cap);
    } else {
        cap = 0;  // workspace too small: k_select takes exact fallback for all
    }

    k_select<<<NCOL / 4, 256, 0, stream>>>(x, cnt, cand, out, cap);
}

// Round 9
// 66.469 us; speedup vs baseline: 2.4383x; 1.0657x over previous
//
#include <hip/hip_runtime.h>
#include <math.h>
#include <stdint.h>

#define B_     32
#define L_     16384
#define C_     128
#define KTOP   64
#define NCOL   (B_ * C_)     // 4096 columns
#define CAPMAX 256           // per-column candidate capacity (4 slots/lane * 64 lanes)
#define CSTR   32            // cnt stride in ints: one counter per 128 B L2 line
#define LSLOT  16            // LDS candidate slots per column per block
#define T0     2.42f         // P(N(0,1)>T0)=0.00776 -> mean n~127, sd~11.2
                             // P(n<64) ~ 7.6e-9/col (3e-5 overall); P(n>256) ~ 0 (11.5 sigma)

typedef float f32x4 __attribute__((ext_vector_type(4)));

// pack (value, index): high32 = float bits (v > T0 > 0 so bit pattern is
// monotonic in value), low32 = index. u64 max == lexicographic (value, index)
// max == JAX stable-argsort tie rule (largest indices win ties).
__device__ __forceinline__ uint64_t pack_cand(float v, int l) {
    return ((uint64_t)__float_as_uint(v) << 32) | (uint32_t)l;
}

// lexicographic (value, index) less-than (fallback path only)
__device__ __forceinline__ bool lex_lt(float v1, int i1, float v2, int i2) {
    return (v1 < v2) || ((v1 == v2) && (i1 < i2));
}

// Zero the padded per-column counters (512 KB).
__global__ __launch_bounds__(256) void k_zero(int* __restrict__ cnt) {
    cnt[blockIdx.x * 256 + threadIdx.x] = 0;
}

// Pass 1 (UNCHANGED from R8): stream x (2 float4 loads in flight per thread),
// LDS-batched compact of values > T0 per column; one padded global atomic per
// (block, column).
__global__ __launch_bounds__(256) void k_filter(const float* __restrict__ x,
                                                int* __restrict__ cnt,
                                                uint64_t* __restrict__ cand,
                                                int cap) {
    __shared__ int      lcnt[C_];
    __shared__ uint64_t lbuf[C_][LSLOT + 1];   // +1: break 128B-stride bank aliasing

    const int tid = threadIdx.x;
    const int b   = blockIdx.y;
    const int l0  = blockIdx.x * 256;
    const int r   = tid >> 5;                  // 0..7 row within group
    const int c4  = tid & 31;                  // float4 slot within row
    const f32x4* xb = (const f32x4*)x + (size_t)b * L_ * (C_ / 4);
    const int clbase = c4 * 4;

    if (tid < C_) lcnt[tid] = 0;
    __syncthreads();

    for (int l = l0 + r; l < l0 + 256; l += 16) {
        f32x4 v0 = xb[(size_t)l * (C_ / 4) + c4];
        f32x4 v1 = xb[(size_t)(l + 8) * (C_ / 4) + c4];
#pragma unroll
        for (int h = 0; h < 2; ++h) {
            const f32x4 v = h ? v1 : v0;
            const int   lr = l + h * 8;
#pragma unroll
            for (int j = 0; j < 4; ++j) {
                float vv = (j == 0) ? v.x : (j == 1) ? v.y : (j == 2) ? v.z : v.w;
                if (vv > T0) {
                    int cl = clbase + j;
                    int p  = atomicAdd(&lcnt[cl], 1);
                    if (p < LSLOT) {
                        lbuf[cl][p] = pack_cand(vv, lr);
                    } else {  // rare overflow: direct global append
                        int g = atomicAdd(&cnt[(b * C_ + cl) * CSTR], 1);
                        if (g < cap) cand[(size_t)(b * C_ + cl) * cap + g] = pack_cand(vv, lr);
                    }
                }
            }
        }
    }
    __syncthreads();

    if (tid < C_) {
        int m = lcnt[tid];
        m = (m > LSLOT) ? LSLOT : m;
        if (m > 0) {
            int col  = b * C_ + tid;
            int base = atomicAdd(&cnt[col * CSTR], m);
            for (int j = 0; j < m; ++j) {
                int p = base + j;
                if (p < cap) cand[(size_t)col * cap + p] = lbuf[tid][j];
            }
        }
    }
}

// Pass 2: ONE WAVE per column. Ballot-based exact selection (no big sort):
// binary-search the 64th-largest value bits (VALU-only: ballot+popc), break
// ties at that value by index (largest indices win, per JAX stable argsort),
// compact the exactly-64 winners into LDS via ballot-prefix slots, then the
// R8-verified 21-level ascending bitonic sort by index -> lane i = out row i.
// Replaces ~264 DS ops of u64 shuffle sort with ~60 DS + ~900 VALU.
__global__ __launch_bounds__(256) void k_select(const float* __restrict__ x,
                                                const int* __restrict__ cnt,
                                                const uint64_t* __restrict__ cand,
                                                float* __restrict__ out,
                                                int cap) {
    __shared__ uint64_t wbuf[4][KTOP];

    const int wave = threadIdx.x >> 6;           // 0..3
    const int lane = threadIdx.x & 63;
    const int col  = blockIdx.x * 4 + wave;
    const int b    = col >> 7;
    const int c    = col & (C_ - 1);

    const int n = (cap > 0) ? cnt[col * CSTR] : 0;

    uint64_t key2;

    if (n >= KTOP && n <= cap) {
        // ---- fast path: candidates into registers (4 slots/lane) ----
        uint32_t vb[4], ix[4];
#pragma unroll
        for (int i = 0; i < 4; ++i) {
            int p = lane + i * 64;
            uint64_t s = (p < n) ? cand[(size_t)col * cap + p] : 0ull;  // 0 = below all
            vb[i] = (uint32_t)(s >> 32);
            ix[i] = (uint32_t)s;
        }
        // exact upper bound: wave-max of value bits
        uint32_t vmax = max(max(vb[0], vb[1]), max(vb[2], vb[3]));
#pragma unroll
        for (int off = 32; off; off >>= 1)
            vmax = max(vmax, (uint32_t)__shfl_xor((int)vmax, off, 64));
        // binary search on value bits: C(p) = #{vb > p}; C(lo)>=64 > C(hi)
        uint32_t lo = __float_as_uint(T0), hi = vmax + 1;
        while (hi - lo > 1) {
            uint32_t mid = lo + ((hi - lo) >> 1);
            int cgt = 0;
#pragma unroll
            for (int i = 0; i < 4; ++i)
                cgt += (int)__popcll(__ballot(vb[i] > mid));
            if (cgt >= KTOP) lo = mid; else hi = mid;
        }
        const uint32_t v64 = lo + 1;   // value bits of the 64th-largest (val,idx) key
        int cgt = 0;
#pragma unroll
        for (int i = 0; i < 4; ++i)
            cgt += (int)__popcll(__ballot(vb[i] > v64));
        const int m = KTOP - cgt;      // winners still needed among ties (>= 1)
        // binary search on index among ties: largest thr with #{tie && idx>=thr} >= m
        uint32_t tlo = 0, thi = L_;
        while (thi - tlo > 1) {
            uint32_t mid = tlo + ((thi - tlo) >> 1);
            int ct = 0;
#pragma unroll
            for (int i = 0; i < 4; ++i)
                ct += (int)__popcll(__ballot(vb[i] == v64 && ix[i] >= mid));
            if (ct >= m) tlo = mid; else thi = mid;
        }
        // compact the 64 winners into LDS at ballot-prefix slots (no atomics,
        // no block barrier -- per-wave buffer, in-order LDS per wave)
        volatile uint64_t* wb = wbuf[wave];
        int base = 0;
#pragma unroll
        for (int i = 0; i < 4; ++i) {
            const bool win = (vb[i] > v64) || (vb[i] == v64 && ix[i] >= tlo);
            const uint64_t msk = __ballot(win);
            if (win) {
                int slot = base + (int)__popcll(msk & ((1ull << lane) - 1ull));
                wb[slot] = ((uint64_t)ix[i] << 32) | vb[i];
            }
            base += (int)__popcll(msk);
        }
        __builtin_amdgcn_wave_barrier();
        key2 = wb[lane];
    } else {
        // ---- exact fallback: lexicographic-descent argmax, 64 rounds ----
        const float* xc = x + (size_t)b * L_ * C_ + c;
        float pv = INFINITY;
        int   pi = 0x7fffffff;
        float keepv = 0.0f;
        int   keepi = 0;
        for (int k = 0; k < KTOP; ++k) {
            float bv = -INFINITY;
            int   bi = -1;
            for (int l = lane; l < L_; l += 64) {
                float vv = xc[(size_t)l * C_];
                if (lex_lt(vv, l, pv, pi) && lex_lt(bv, bi, vv, l)) {
                    bv = vv; bi = l;
                }
            }
#pragma unroll
            for (int off = 32; off; off >>= 1) {
                float ov = __shfl_xor(bv, off, 64);
                int   oi = __shfl_xor(bi, off, 64);
                if (lex_lt(bv, bi, ov, oi)) { bv = ov; bi = oi; }
            }
            pv = bv; pi = bi;
            if (lane == k) { keepv = bv; keepi = bi; }
        }
        key2 = ((uint64_t)(uint32_t)keepi << 32) | __float_as_uint(keepv);
    }

    // temporal reorder (R8-verified): 64-lane ascending bitonic sort on
    // key2 = (index, value) -- indices unique -> strict order. Lane i = row i.
#pragma unroll
    for (int k = 2; k <= 64; k <<= 1) {
#pragma unroll
        for (int j = k >> 1; j >= 1; j >>= 1) {
            const bool upper = (lane & j) != 0;
            uint64_t o = __shfl_xor((unsigned long long)key2, j, 64);
            const bool km = ((lane & k) != 0);      // ascending block?
            const bool take_max = (km != upper);
            const bool gt = key2 > o;
            key2 = (take_max == gt) ? key2 : o;
        }
    }
    out[((size_t)b * KTOP + lane) * C_ + c] =
        __uint_as_float((uint32_t)(key2 & 0xffffffffull));
}

extern "C" void kernel_launch(void* const* d_in, const int* in_sizes, int n_in,
                              void* d_out, int out_size, void* d_ws, size_t ws_size,
                              hipStream_t stream) {
    (void)in_sizes; (void)n_in; (void)out_size;
    const float* x  = (const float*)d_in[0];
    float*      out = (float*)d_out;

    int*   cnt       = (int*)d_ws;
    size_t cnt_bytes = (size_t)NCOL * CSTR * sizeof(int);   // 512 KB, padded

    // size the candidate buffer from the workspace we actually have
    int cap = 0;
    if (ws_size > cnt_bytes) {
        size_t rem = ws_size - cnt_bytes;
        size_t c   = rem / ((size_t)NCOL * 8);  // 8 B per packed slot
        cap = (c > CAPMAX) ? CAPMAX : (int)c;
    }
    uint64_t* cand = (uint64_t*)((char*)d_ws + cnt_bytes);

    if (cap >= KTOP) {
        k_zero<<<(NCOL * CSTR) / 256, 256, 0, stream>>>(cnt);
        dim3 g1(L_ / 256, B_);
        k_filter<<<g1, 256, 0, stream>>>(x, cnt, cand, cap);
    } else {
        cap = 0;  // workspace too small: k_select takes exact fallback for all
    }

    k_select<<<NCOL / 4, 256, 0, stream>>>(x, cnt, cand, out, cap);
}

// Round 10
// 64.840 us; speedup vs baseline: 2.4995x; 1.0251x over previous
//
#include <hip/hip_runtime.h>
#include <math.h>
#include <stdint.h>

#define B_     32
#define L_     16384
#define C_     128
#define KTOP   64
#define NCOL   (B_ * C_)     // 4096 columns
#define CAPMAX 256           // per-column candidate capacity (4 slots/lane * 64 lanes)
#define CSTR   32            // cnt stride in ints: one counter per 128 B L2 line
#define LSLOT  16            // LDS candidate slots per column per block
#define T0     2.42f         // P(N(0,1)>T0)=0.00776 -> mean n~127, sd~11.2
                             // P(n<64) ~ 7.6e-9/col (3e-5 overall); P(n>256) ~ 0 (11.5 sigma)

typedef float f32x4 __attribute__((ext_vector_type(4)));

// pack (value, index): high32 = float bits (v > T0 > 0 so bit pattern is
// monotonic in value), low32 = index. u64 max == lexicographic (value, index)
// max == JAX stable-argsort tie rule (largest indices win ties).
__device__ __forceinline__ uint64_t pack_cand(float v, int l) {
    return ((uint64_t)__float_as_uint(v) << 32) | (uint32_t)l;
}

// lexicographic (value, index) less-than (fallback path only)
__device__ __forceinline__ bool lex_lt(float v1, int i1, float v2, int i2) {
    return (v1 < v2) || ((v1 == v2) && (i1 < i2));
}

// Zero the padded per-column counters (512 KB).
__global__ __launch_bounds__(256) void k_zero(int* __restrict__ cnt) {
    cnt[blockIdx.x * 256 + threadIdx.x] = 0;
}

// Pass 1: stream x with 4 float4 loads in flight per thread (32-row stride),
// quad-max pre-test (97% of quads skip the per-element branches at T0=2.42),
// LDS-batched compact; one padded global atomic per (block, column).
__global__ __launch_bounds__(256) void k_filter(const float* __restrict__ x,
                                                int* __restrict__ cnt,
                                                uint64_t* __restrict__ cand,
                                                int cap) {
    __shared__ int      lcnt[C_];
    __shared__ uint64_t lbuf[C_][LSLOT + 1];   // +1: break 128B-stride bank aliasing

    const int tid = threadIdx.x;
    const int b   = blockIdx.y;
    const int l0  = blockIdx.x * 256;
    const int r   = tid >> 5;                  // 0..7 row within group
    const int c4  = tid & 31;                  // float4 slot within row
    const f32x4* xc = (const f32x4*)x + (size_t)b * L_ * (C_ / 4) + c4;
    const int clbase = c4 * 4;

    if (tid < C_) lcnt[tid] = 0;
    __syncthreads();

    for (int l = l0 + r; l < l0 + 256; l += 32) {
        f32x4 v0 = xc[(l +  0) * (C_ / 4)];
        f32x4 v1 = xc[(l +  8) * (C_ / 4)];
        f32x4 v2 = xc[(l + 16) * (C_ / 4)];
        f32x4 v3 = xc[(l + 24) * (C_ / 4)];
#pragma unroll
        for (int h = 0; h < 4; ++h) {
            const f32x4 v = (h == 0) ? v0 : (h == 1) ? v1 : (h == 2) ? v2 : v3;
            const int   lr = l + h * 8;
            // quad-max pre-test: skip per-element branch blocks when no hit
            if (fmaxf(fmaxf(v.x, v.y), fmaxf(v.z, v.w)) > T0) {
#pragma unroll
                for (int j = 0; j < 4; ++j) {
                    float vv = (j == 0) ? v.x : (j == 1) ? v.y : (j == 2) ? v.z : v.w;
                    if (vv > T0) {
                        int cl = clbase + j;
                        int p  = atomicAdd(&lcnt[cl], 1);
                        if (p < LSLOT) {
                            lbuf[cl][p] = pack_cand(vv, lr);
                        } else {  // rare overflow: direct global append
                            int g = atomicAdd(&cnt[(b * C_ + cl) * CSTR], 1);
                            if (g < cap) cand[(size_t)(b * C_ + cl) * cap + g] = pack_cand(vv, lr);
                        }
                    }
                }
            }
        }
    }
    __syncthreads();

    if (tid < C_) {
        int m = lcnt[tid];
        m = (m > LSLOT) ? LSLOT : m;
        if (m > 0) {
            int col  = b * C_ + tid;
            int base = atomicAdd(&cnt[col * CSTR], m);
            for (int j = 0; j < m; ++j) {
                int p = base + j;
                if (p < cap) cand[(size_t)col * cap + p] = lbuf[tid][j];
            }
        }
    }
}

// Pass 2 (UNCHANGED from R9): ONE WAVE per column. Ballot-based exact
// selection: binary-search the 64th-largest value bits (VALU-only), break
// ties by index (largest indices win, per JAX stable argsort), compact the
// exactly-64 winners into LDS via ballot-prefix slots, then a 21-level
// ascending bitonic sort by index -> lane i = out row i.
__global__ __launch_bounds__(256) void k_select(const float* __restrict__ x,
                                                const int* __restrict__ cnt,
                                                const uint64_t* __restrict__ cand,
                                                float* __restrict__ out,
                                                int cap) {
    __shared__ uint64_t wbuf[4][KTOP];

    const int wave = threadIdx.x >> 6;           // 0..3
    const int lane = threadIdx.x & 63;
    const int col  = blockIdx.x * 4 + wave;
    const int b    = col >> 7;
    const int c    = col & (C_ - 1);

    const int n = (cap > 0) ? cnt[col * CSTR] : 0;

    uint64_t key2;

    if (n >= KTOP && n <= cap) {
        // ---- fast path: candidates into registers (4 slots/lane) ----
        uint32_t vb[4], ix[4];
#pragma unroll
        for (int i = 0; i < 4; ++i) {
            int p = lane + i * 64;
            uint64_t s = (p < n) ? cand[(size_t)col * cap + p] : 0ull;  // 0 = below all
            vb[i] = (uint32_t)(s >> 32);
            ix[i] = (uint32_t)s;
        }
        // exact upper bound: wave-max of value bits
        uint32_t vmax = max(max(vb[0], vb[1]), max(vb[2], vb[3]));
#pragma unroll
        for (int off = 32; off; off >>= 1)
            vmax = max(vmax, (uint32_t)__shfl_xor((int)vmax, off, 64));
        // binary search on value bits: C(p) = #{vb > p}; C(lo)>=64 > C(hi)
        uint32_t lo = __float_as_uint(T0), hi = vmax + 1;
        while (hi - lo > 1) {
            uint32_t mid = lo + ((hi - lo) >> 1);
            int cgt = 0;
#pragma unroll
            for (int i = 0; i < 4; ++i)
                cgt += (int)__popcll(__ballot(vb[i] > mid));
            if (cgt >= KTOP) lo = mid; else hi = mid;
        }
        const uint32_t v64 = lo + 1;   // value bits of the 64th-largest (val,idx) key
        int cgt = 0;
#pragma unroll
        for (int i = 0; i < 4; ++i)
            cgt += (int)__popcll(__ballot(vb[i] > v64));
        const int m = KTOP - cgt;      // winners still needed among ties (>= 1)
        // binary search on index among ties: largest thr with #{tie && idx>=thr} >= m
        uint32_t tlo = 0, thi = L_;
        while (thi - tlo > 1) {
            uint32_t mid = tlo + ((thi - tlo) >> 1);
            int ct = 0;
#pragma unroll
            for (int i = 0; i < 4; ++i)
                ct += (int)__popcll(__ballot(vb[i] == v64 && ix[i] >= mid));
            if (ct >= m) tlo = mid; else thi = mid;
        }
        // compact the 64 winners into LDS at ballot-prefix slots (no atomics,
        // no block barrier -- per-wave buffer, in-order LDS per wave)
        volatile uint64_t* wb = wbuf[wave];
        int base = 0;
#pragma unroll
        for (int i = 0; i < 4; ++i) {
            const bool win = (vb[i] > v64) || (vb[i] == v64 && ix[i] >= tlo);
            const uint64_t msk = __ballot(win);
            if (win) {
                int slot = base + (int)__popcll(msk & ((1ull << lane) - 1ull));
                wb[slot] = ((uint64_t)ix[i] << 32) | vb[i];
            }
            base += (int)__popcll(msk);
        }
        __builtin_amdgcn_wave_barrier();
        key2 = wb[lane];
    } else {
        // ---- exact fallback: lexicographic-descent argmax, 64 rounds ----
        const float* xc = x + (size_t)b * L_ * C_ + c;
        float pv = INFINITY;
        int   pi = 0x7fffffff;
        float keepv = 0.0f;
        int   keepi = 0;
        for (int k = 0; k < KTOP; ++k) {
            float bv = -INFINITY;
            int   bi = -1;
            for (int l = lane; l < L_; l += 64) {
                float vv = xc[(size_t)l * C_];
                if (lex_lt(vv, l, pv, pi) && lex_lt(bv, bi, vv, l)) {
                    bv = vv; bi = l;
                }
            }
#pragma unroll
            for (int off = 32; off; off >>= 1) {
                float ov = __shfl_xor(bv, off, 64);
                int   oi = __shfl_xor(bi, off, 64);
                if (lex_lt(bv, bi, ov, oi)) { bv = ov; bi = oi; }
            }
            pv = bv; pi = bi;
            if (lane == k) { keepv = bv; keepi = bi; }
        }
        key2 = ((uint64_t)(uint32_t)keepi << 32) | __float_as_uint(keepv);
    }

    // temporal reorder: 64-lane ascending bitonic sort on key2 = (index, value)
    // (indices unique -> strict order). Lane i then holds output row i.
#pragma unroll
    for (int k = 2; k <= 64; k <<= 1) {
#pragma unroll
        for (int j = k >> 1; j >= 1; j >>= 1) {
            const bool upper = (lane & j) != 0;
            uint64_t o = __shfl_xor((unsigned long long)key2, j, 64);
            const bool km = ((lane & k) != 0);      // ascending block?
            const bool take_max = (km != upper);
            const bool gt = key2 > o;
            key2 = (take_max == gt) ? key2 : o;
        }
    }
    out[((size_t)b * KTOP + lane) * C_ + c] =
        __uint_as_float((uint32_t)(key2 & 0xffffffffull));
}

extern "C" void kernel_launch(void* const* d_in, const int* in_sizes, int n_in,
                              void* d_out, int out_size, void* d_ws, size_t ws_size,
                              hipStream_t stream) {
    (void)in_sizes; (void)n_in; (void)out_size;
    const float* x  = (const float*)d_in[0];
    float*      out = (float*)d_out;

    int*   cnt       = (int*)d_ws;
    size_t cnt_bytes = (size_t)NCOL * CSTR * sizeof(int);   // 512 KB, padded

    // size the candidate buffer from the workspace we actually have
    int cap = 0;
    if (ws_size > cnt_bytes) {
        size_t rem = ws_size - cnt_bytes;
        size_t c   = rem / ((size_t)NCOL * 8);  // 8 B per packed slot
        cap = (c > CAPMAX) ? CAPMAX : (int)c;
    }
    uint64_t* cand = (uint64_t*)((char*)d_ws + cnt_bytes);

    if (cap >= KTOP) {
        k_zero<<<(NCOL * CSTR) / 256, 256, 0, stream>>>(cnt);
        dim3 g1(L_ / 256, B_);
        k_filter<<<g1, 256, 0, stream>>>(x, cnt, cand, cap);
    } else {
        cap = 0;  // workspace too small: k_select takes exact fallback for all
    }

    k_select<<<NCOL / 4, 256, 0, stream>>>(x, cnt, cand, out, cap);
}